// Round 3
// baseline (218.067 us; speedup 1.0000x reference)
//
#include <hip/hip_runtime.h>
#include <math.h>

#define SEQ 2048
#define EMB 1024
#define NH  16
#define HD  64

typedef __attribute__((ext_vector_type(8))) short short8;   // 8 bf16 = 4 VGPRs
typedef __attribute__((ext_vector_type(4))) float f32x4;    // MFMA acc

static const size_t XE = (size_t)2 * SEQ * EMB;  // 4,194,304 elems
static const size_t WE = (size_t)EMB * EMB;      // 1,048,576 elems

// RNE float -> bf16 bits (inputs finite)
static __device__ __forceinline__ short f2bf(float f) {
    unsigned u = __builtin_bit_cast(unsigned, f);
    u = u + 0x7fffu + ((u >> 16) & 1u);
    return (short)(u >> 16);
}

#if __has_builtin(__builtin_amdgcn_cvt_pk_bf16_f32)
typedef __attribute__((ext_vector_type(2))) __bf16 bf16x2;
static __device__ __forceinline__ unsigned pk2(float a, float b) {
    bf16x2 v = __builtin_amdgcn_cvt_pk_bf16_f32(a, b);
    return __builtin_bit_cast(unsigned, v);
}
#else
static __device__ __forceinline__ unsigned pk2(float a, float b) {
    return (unsigned)(unsigned short)f2bf(a) |
           ((unsigned)(unsigned short)f2bf(b) << 16);
}
#endif

static __device__ __forceinline__ short8 cvt8(float4 a, float4 b) {
    union { unsigned u[4]; short8 s; } r;
    r.u[0] = pk2(a.x, a.y); r.u[1] = pk2(a.z, a.w);
    r.u[2] = pk2(b.x, b.y); r.u[3] = pk2(b.z, b.w);
    return r.s;
}

// async global->LDS, 16B/lane; LDS dest = wave-uniform base + lane*16
static __device__ __forceinline__ void gload16(const void* g, void* l) {
    __builtin_amdgcn_global_load_lds(
        (const __attribute__((address_space(1))) void*)g,
        (__attribute__((address_space(3))) void*)l, 16, 0, 0);
}

// ---------------------------------------------------------------------------
// Pre-pass: convert X (q,k,v activations) AND the three weight matrices to
// bf16. Memory-bound (~90MB total), layout-preserving.
//   blocks [0,6144): X   (3 segs x 2048 blocks, 4M elems each)
//   blocks [6144,7680): W (3 segs x 512 blocks, 1M elems each)
// ---------------------------------------------------------------------------
__global__ __launch_bounds__(256)
void cvt_all(const float* __restrict__ xq, const float* __restrict__ xk,
             const float* __restrict__ xv, const float* __restrict__ wq,
             const float* __restrict__ wk, const float* __restrict__ wv,
             short* __restrict__ dxq, short* __restrict__ dxk,
             short* __restrict__ dxv, short* __restrict__ dw) {
    int id = blockIdx.x;
    const float* s; short* d; size_t i;
    if (id < 6144) {
        int seg = id >> 11, o = id & 2047;
        s = (seg == 0) ? xq : (seg == 1) ? xk : xv;
        d = (seg == 0) ? dxq : (seg == 1) ? dxk : dxv;
        i = (size_t)o * 256 + threadIdx.x;
    } else {
        int wid = id - 6144;
        int seg = wid >> 9, o = wid & 511;
        s = (seg == 0) ? wq : (seg == 1) ? wk : wv;
        d = dw + (size_t)seg * WE;
        i = (size_t)o * 256 + threadIdx.x;
    }
    const float4* sp = (const float4*)s;
    float4 a = sp[2 * i], b = sp[2 * i + 1];
    *(short8*)(d + i * 8) = cvt8(a, b);
}

// ---------------------------------------------------------------------------
// Projection GEMM, round 9: BK=64 (was 32) on the verified round-8 skeleton.
// Same sync structure (barrier -> prefetch p^1 via global_load_lds ->
// ds_read p -> MFMA); only the period size doubles:
//  - 16 barrier periods (was 32); 32 MFMA + 16 ds_read_b128 per wave/period
//    -> twice the latency-hiding work per vmcnt(0) barrier drain.
//  - LDS 64KB (2buf x [X 16KB + W 16KB]) -> still 2 blocks/CU (measured
//    occupancy was already ~2 blocks/CU, so no loss).
//  - chunk-major slots: slot = c*128 + row, c = 8-bf16 K-chunk in [0,8).
//    Fragment reads are 256B-contiguous per quad -> conflict-free (r8: 0).
// ---------------------------------------------------------------------------
#define ES_STRIDE 136
__global__ __launch_bounds__(256, 2)
void proj(const short* __restrict__ Xq, const short* __restrict__ Xk,
          const short* __restrict__ Xv, const short* __restrict__ Wb,
          short* __restrict__ qb, short* __restrict__ kbuf,
          short* __restrict__ vt) {
    __shared__ __align__(16) char lds_raw[65536];
    short8* Fs = (short8*)lds_raw;             // [2][1024] bf16 X tiles, 32KB
    short8* Hs = (short8*)(lds_raw + 32768);   // [2][1024] bf16 W tiles, 32KB
    short*  Es = (short*)lds_raw;              // epilogue 128 x 136, 34KB

    const int L = blockIdx.x;
    const int xcd = L & 7, i = L >> 3;   // i 0..95
    const int z = i >> 5;                // 0..2
    const int m = i & 31;
    const int ty = xcd * 4 + (m & 3);    // 0..31  (X strip)
    const int tx = m >> 2;               // 0..7   (W strip)

    const short* Fop; const short* Hop; short* C;
    if (z == 0)      { Fop = Xq; Hop = Wb;           C = qb;   }
    else if (z == 1) { Fop = Xk; Hop = Wb + WE;      C = kbuf; }
    else             { Fop = Xv; Hop = Wb + 2 * WE;  C = vt;   }
    const int fr0 = ty * 128;   // X rows
    const int hr0 = tx * 128;   // W rows

    const int t = threadIdx.x, w = t >> 6, lane = t & 63;
    const int l15 = lane & 15, quad = lane >> 4;
    const int mh = (w >> 1) * 64, nh2 = (w & 1) * 64;

    // stage a 128x64 bf16 tile: slot g = c*128 + row, 4 gload16 per thread
    auto stageF = [&](int pp, int k0) {
#pragma unroll
        for (int j = 0; j < 4; ++j) {
            int g = j * 256 + t, row = g & 127, c = g >> 7;
            gload16(Fop + (size_t)(fr0 + row) * EMB + k0 + c * 8,
                    &Fs[pp * 1024 + j * 256 + w * 64]);
        }
    };
    auto stageH = [&](int pp, int k0) {
#pragma unroll
        for (int j = 0; j < 4; ++j) {
            int g = j * 256 + t, row = g & 127, c = g >> 7;
            gload16(Hop + (size_t)(hr0 + row) * EMB + k0 + c * 8,
                    &Hs[pp * 1024 + j * 256 + w * 64]);
        }
    };

    f32x4 acc[4][4];
#pragma unroll
    for (int a = 0; a < 4; ++a)
#pragma unroll
        for (int b = 0; b < 4; ++b) acc[a][b] = 0.f;

    stageF(0, 0);
    stageH(0, 0);

    int p = 0;
    for (int k0 = 0; k0 < EMB; k0 += 64, p ^= 1) {
        __syncthreads();   // drains prev-iter gload_lds into buffer p
        if (k0 + 64 < EMB) { stageF(p ^ 1, k0 + 64); stageH(p ^ 1, k0 + 64); }

        short8 af[2][4], bf[2][4];
        if (z < 2) {
#pragma unroll
            for (int kb2 = 0; kb2 < 2; ++kb2) {
#pragma unroll
                for (int mi = 0; mi < 4; ++mi)
                    af[kb2][mi] = Fs[p * 1024 + (kb2 * 4 + quad) * 128 +
                                     mh + mi * 16 + l15];
#pragma unroll
                for (int ni = 0; ni < 4; ++ni)
                    bf[kb2][ni] = Hs[p * 1024 + (kb2 * 4 + quad) * 128 +
                                     nh2 + ni * 16 + l15];
            }
        } else {
#pragma unroll
            for (int kb2 = 0; kb2 < 2; ++kb2) {
#pragma unroll
                for (int mi = 0; mi < 4; ++mi)
                    af[kb2][mi] = Hs[p * 1024 + (kb2 * 4 + quad) * 128 +
                                     mh + mi * 16 + l15];
#pragma unroll
                for (int ni = 0; ni < 4; ++ni)
                    bf[kb2][ni] = Fs[p * 1024 + (kb2 * 4 + quad) * 128 +
                                     nh2 + ni * 16 + l15];
            }
        }
#pragma unroll
        for (int kb2 = 0; kb2 < 2; ++kb2)
#pragma unroll
            for (int mi = 0; mi < 4; ++mi)
#pragma unroll
                for (int ni = 0; ni < 4; ++ni)
                    acc[mi][ni] = __builtin_amdgcn_mfma_f32_16x16x32_bf16(
                        af[kb2][mi], bf[kb2][ni], acc[mi][ni], 0, 0, 0);
    }

    __syncthreads();
#pragma unroll
    for (int mi = 0; mi < 4; ++mi)
#pragma unroll
        for (int ni = 0; ni < 4; ++ni)
#pragma unroll
            for (int r = 0; r < 4; ++r) {
                int lr_ = mh + mi * 16 + quad * 4 + r;
                int lc_ = nh2 + ni * 16 + l15;
                Es[lr_ * ES_STRIDE + lc_] = f2bf(acc[mi][ni][r]);
            }
    __syncthreads();
    {
        int row = t >> 1, half = t & 1;
        const short* src = Es + row * ES_STRIDE + half * 64;
        short* dst;
        if (z < 2) {
            dst = C + (size_t)(fr0 + row) * EMB + hr0 + half * 64;
        } else {
            int bz = fr0 >> 11, s0 = fr0 & 2047;
            dst = C + ((size_t)bz * EMB + hr0 + row) * SEQ + s0 + half * 64;
        }
#pragma unroll
        for (int j = 0; j < 8; ++j)
            *(short8*)(dst + j * 8) = *(const short8*)(src + j * 8);
    }
}

// ---------------------------------------------------------------------------
// Flash attention, bf16 MFMA, fixed-max softmax, S^T trick (unchanged).
// ---------------------------------------------------------------------------
__global__ __launch_bounds__(256, 2)
void attn_mfma(const short* __restrict__ Qg, const short* __restrict__ Kg,
               const short* __restrict__ Vtg, float* __restrict__ OutD) {
    __shared__ short8 QPs[1024];     // Q then P: [row(128)][c(8)^] 16KB
    __shared__ short8 Ks[2][1024];   // dbuf [krow(128)][dchunk(8)^] 32KB
    __shared__ short8 Vs[2][1024];   // dbuf [half(2)][drow(64)][kc(8)^] 32KB

    const int t = threadIdx.x, w = t >> 6, lane = t & 63;
    const int l15 = lane & 15, quad = lane >> 4;
    const int lr3 = lane >> 3, lc7 = lane & 7;   // staging row/chunk split
    const int L = blockIdx.x;
    const int xcd = L & 7, i = L >> 3;        // i 0..63
    const int bh = xcd * 4 + (i & 3);         // 0..31
    const int q0 = (i >> 2) * 128;            // 16 q-tiles
    const int b = bh >> 4, h = bh & 15;
    const short* Qb = Qg + (size_t)b * SEQ * EMB + h * HD;
    const short* Kb = Kg + (size_t)b * SEQ * EMB + h * HD;
    const short* Vb = Vtg + ((size_t)b * EMB + h * HD) * SEQ;

    // staging: one gload16 = 8 rows x 128B coalesced, XOR placement
    auto stageKV = [&](int p, int kt) {
#pragma unroll
        for (int j = 0; j < 4; ++j) {
            int rb = w * 32 + j * 8;                 // K key-rows
            int krow = rb + lr3;
            gload16(Kb + (size_t)(kt + krow) * EMB + ((lc7 ^ (krow & 7)) * 8),
                    &Ks[p][rb * 8]);
            int half = w >> 1, db = (w & 1) * 32 + j * 8;   // V d-rows
            int d = db + lr3;
            gload16(Vb + (size_t)d * SEQ + kt + half * 64 + ((lc7 ^ (d & 7)) * 8),
                    &Vs[p][half * 512 + db * 8]);
        }
    };

    // prologue: Q tile + period 0
#pragma unroll
    for (int j = 0; j < 4; ++j) {
        int rb = w * 32 + j * 8;
        int row = rb + lr3;
        gload16(Qb + (size_t)(q0 + row) * EMB + ((lc7 ^ (row & 7)) * 8),
                &QPs[rb * 8]);
    }
    stageKV(0, 0);
    __syncthreads();   // drains prologue loads

    // hoist Q fragments (B-operand, lane l15 = q); wave-private rows, so no
    // barrier needed before P reuses this region.
    short8 qf[2][2];
#pragma unroll
    for (int qi = 0; qi < 2; ++qi)
#pragma unroll
        for (int kb2 = 0; kb2 < 2; ++kb2) {
            int row = w * 32 + qi * 16 + l15;
            qf[qi][kb2] = QPs[row * 8 + ((kb2 * 4 + quad) ^ (l15 & 7))];
        }

    f32x4 o[2][4];
    float lr[2] = {0.f, 0.f};
#pragma unroll
    for (int qi = 0; qi < 2; ++qi)
#pragma unroll
        for (int ni = 0; ni < 4; ++ni) o[qi][ni] = 0.f;
    const float cl2 = 0.18033688011112042f;   // (1/8) * log2(e)
    const float c0  = 11.541560327111707f;    // 64 * cl2

    int p = 0;
    for (int kt = 0; kt < SEQ; kt += 128, p ^= 1) {
        if (kt) __syncthreads();   // drains buf-p loads (issued last period)
        if (kt + 128 < SEQ) stageKV(p ^ 1, kt + 128);

#pragma unroll
        for (int half = 0; half < 2; ++half) {
            // ---- T = K Q^T : rows = key (64 of this half), cols = q ----
            f32x4 s[4][2];
#pragma unroll
            for (int kblk = 0; kblk < 4; ++kblk)
#pragma unroll
                for (int qi = 0; qi < 2; ++qi) s[kblk][qi] = 0.f;
#pragma unroll
            for (int kb2 = 0; kb2 < 2; ++kb2) {
                short8 ak[4];
#pragma unroll
                for (int kblk = 0; kblk < 4; ++kblk) {
                    int row = half * 64 + kblk * 16 + l15;
                    ak[kblk] = Ks[p][row * 8 + ((kb2 * 4 + quad) ^ (l15 & 7))];
                }
#pragma unroll
                for (int kblk = 0; kblk < 4; ++kblk)
#pragma unroll
                    for (int qi = 0; qi < 2; ++qi)
                        s[kblk][qi] = __builtin_amdgcn_mfma_f32_16x16x32_bf16(
                            ak[kblk], qf[qi][kb2], s[kblk][qi], 0, 0, 0);
            }

            // ---- fixed-max softmax + packed b64 P write ----
#pragma unroll
            for (int qi = 0; qi < 2; ++qi) {
                int row = w * 32 + qi * 16 + l15;
#pragma unroll
                for (int kblk = 0; kblk < 4; ++kblk) {
                    float p0 = __builtin_amdgcn_exp2f(fmaf(s[kblk][qi][0], cl2, -c0));
                    float p1 = __builtin_amdgcn_exp2f(fmaf(s[kblk][qi][1], cl2, -c0));
                    float p2 = __builtin_amdgcn_exp2f(fmaf(s[kblk][qi][2], cl2, -c0));
                    float p3 = __builtin_amdgcn_exp2f(fmaf(s[kblk][qi][3], cl2, -c0));
                    lr[qi] += (p0 + p1) + (p2 + p3);
                    uint2 pv; pv.x = pk2(p0, p1); pv.y = pk2(p2, p3);
                    int kc = kblk * 2 + (quad >> 1);
                    *(uint2*)((char*)QPs +
                        (((row * 8 + (kc ^ (l15 & 7))) << 4) | ((quad & 1) << 3)))
                        = pv;
                }
            }
            // no barrier: wave reads back only its own q rows (same-wave RAW)

            // ---- O += P V ----
#pragma unroll
            for (int kb2 = 0; kb2 < 2; ++kb2) {
                short8 ap[2], bv[4];
#pragma unroll
                for (int qi = 0; qi < 2; ++qi) {
                    int row = w * 32 + qi * 16 + l15;
                    ap[qi] = QPs[row * 8 + ((kb2 * 4 + quad) ^ (l15 & 7))];
                }
#pragma unroll
                for (int ni = 0; ni < 4; ++ni) {
                    int dr = ni * 16 + l15;
                    bv[ni] = Vs[p][half * 512 + dr * 8 +
                                   ((kb2 * 4 + quad) ^ (l15 & 7))];
                }
#pragma unroll
                for (int qi = 0; qi < 2; ++qi)
#pragma unroll
                    for (int ni = 0; ni < 4; ++ni)
                        o[qi][ni] = __builtin_amdgcn_mfma_f32_16x16x32_bf16(
                            ap[qi], bv[ni], o[qi][ni], 0, 0, 0);
            }
        }
    }

    // ---- epilogue: reduce l across quads, normalize, store fp32 ----
#pragma unroll
    for (int qi = 0; qi < 2; ++qi) {
        float l = lr[qi];
        l += __shfl_xor(l, 16);
        l += __shfl_xor(l, 32);
        lr[qi] = l;
    }
#pragma unroll
    for (int qi = 0; qi < 2; ++qi)
#pragma unroll
        for (int r = 0; r < 4; ++r) {
            float inv = 1.0f / __shfl(lr[qi], quad * 4 + r);
            int q = q0 + w * 32 + qi * 16 + quad * 4 + r;
            float* op = OutD + ((size_t)b * SEQ + q) * EMB + h * HD;
#pragma unroll
            for (int ni = 0; ni < 4; ++ni)
                op[ni * 16 + l15] = o[qi][ni][r] * inv;
        }
}

// ---------------------------------------------------------------------------
extern "C" void kernel_launch(void* const* d_in, const int* in_sizes, int n_in,
                              void* d_out, int out_size, void* d_ws, size_t ws_size,
                              hipStream_t stream) {
    const float* values  = (const float*)d_in[0];
    const float* keys    = (const float*)d_in[1];
    const float* queries = (const float*)d_in[2];
    const float* Wv      = (const float*)d_in[3];
    const float* Wk      = (const float*)d_in[4];
    const float* Wq      = (const float*)d_in[5];
    float* out = (float*)d_out;

    // ws: qb, kb, vt (8MB each) + wb (6MB) + xq, xk, xv bf16 (8MB each) = 54MB
    short* qb  = (short*)d_ws;
    short* kb  = qb + XE;
    short* vt  = kb + XE;
    short* wb  = vt + XE;          // 3*WE
    short* xqb = wb + 3 * WE;
    short* xkb = xqb + XE;
    short* xvb = xkb + XE;

    cvt_all<<<7680, 256, 0, stream>>>(queries, keys, values, Wq, Wk, Wv,
                                      xqb, xkb, xvb, wb);
    proj<<<768, 256, 0, stream>>>(xqb, xkb, xvb, wb, qb, kb, vt);
    attn_mfma<<<512, 256, 0, stream>>>(qb, kb, vt, out);
}

// Round 4
// 210.280 us; speedup vs baseline: 1.0370x; 1.0370x over previous
//
#include <hip/hip_runtime.h>
#include <math.h>

#define SEQ 2048
#define EMB 1024
#define NH  16
#define HD  64

typedef __attribute__((ext_vector_type(8))) short short8;   // 8 bf16 = 4 VGPRs
typedef __attribute__((ext_vector_type(4))) float f32x4;    // MFMA acc

static const size_t XE = (size_t)2 * SEQ * EMB;  // 4,194,304 elems
static const size_t WE = (size_t)EMB * EMB;      // 1,048,576 elems

// RNE float -> bf16 bits (inputs finite)
static __device__ __forceinline__ short f2bf(float f) {
    unsigned u = __builtin_bit_cast(unsigned, f);
    u = u + 0x7fffu + ((u >> 16) & 1u);
    return (short)(u >> 16);
}

#if __has_builtin(__builtin_amdgcn_cvt_pk_bf16_f32)
typedef __attribute__((ext_vector_type(2))) __bf16 bf16x2;
static __device__ __forceinline__ unsigned pk2(float a, float b) {
    bf16x2 v = __builtin_amdgcn_cvt_pk_bf16_f32(a, b);
    return __builtin_bit_cast(unsigned, v);
}
#else
static __device__ __forceinline__ unsigned pk2(float a, float b) {
    return (unsigned)(unsigned short)f2bf(a) |
           ((unsigned)(unsigned short)f2bf(b) << 16);
}
#endif

static __device__ __forceinline__ short8 cvt8(float4 a, float4 b) {
    union { unsigned u[4]; short8 s; } r;
    r.u[0] = pk2(a.x, a.y); r.u[1] = pk2(a.z, a.w);
    r.u[2] = pk2(b.x, b.y); r.u[3] = pk2(b.z, b.w);
    return r.s;
}

// async global->LDS, 16B/lane; LDS dest = wave-uniform base + lane*16
static __device__ __forceinline__ void gload16(const void* g, void* l) {
    __builtin_amdgcn_global_load_lds(
        (const __attribute__((address_space(1))) void*)g,
        (__attribute__((address_space(3))) void*)l, 16, 0, 0);
}

// ---------------------------------------------------------------------------
// Pre-pass: convert X (q,k,v activations) AND the three weight matrices to
// bf16. Memory-bound (~90MB total), layout-preserving.
//   blocks [0,6144): X   (3 segs x 2048 blocks, 4M elems each)
//   blocks [6144,7680): W (3 segs x 512 blocks, 1M elems each)
// ---------------------------------------------------------------------------
__global__ __launch_bounds__(256)
void cvt_all(const float* __restrict__ xq, const float* __restrict__ xk,
             const float* __restrict__ xv, const float* __restrict__ wq,
             const float* __restrict__ wk, const float* __restrict__ wv,
             short* __restrict__ dxq, short* __restrict__ dxk,
             short* __restrict__ dxv, short* __restrict__ dw) {
    int id = blockIdx.x;
    const float* s; short* d; size_t i;
    if (id < 6144) {
        int seg = id >> 11, o = id & 2047;
        s = (seg == 0) ? xq : (seg == 1) ? xk : xv;
        d = (seg == 0) ? dxq : (seg == 1) ? dxk : dxv;
        i = (size_t)o * 256 + threadIdx.x;
    } else {
        int wid = id - 6144;
        int seg = wid >> 9, o = wid & 511;
        s = (seg == 0) ? wq : (seg == 1) ? wk : wv;
        d = dw + (size_t)seg * WE;
        i = (size_t)o * 256 + threadIdx.x;
    }
    const float4* sp = (const float4*)s;
    float4 a = sp[2 * i], b = sp[2 * i + 1];
    *(short8*)(d + i * 8) = cvt8(a, b);
}

// ---------------------------------------------------------------------------
// Projection GEMM, round 10: counted-vmcnt pipeline (T3/T4 graft) on the
// verified round-8 body. BK=32, chunk-major, conflict-free reads — identical
// fragment/MFMA/epilogue code to r8. Changes ONLY the staging schedule:
//  - TRIPLE-buffered LDS (3 x [X 8KB + W 8KB] = 48KB): iter j computes B_j,
//    stages B_{j+2}. Each load batch gets ~2 compute periods to land.
//  - s_waitcnt vmcnt(4) + raw s_barrier instead of __syncthreads: drains
//    exactly B_j's 4 per-wave loads, keeps B_{j+1}'s 4 in flight (never
//    vmcnt(0) in steady state — the m218-measured lever).
//  Per-wave ledger: top of iter j outstanding = 8 (4 B_j + 4 B_{j+1});
//  wait 4 -> B_j complete; barrier -> ALL waves' B_j complete and all
//  readers of B_{j+2}(=B_{j-1}) retired; then stage B_{j+2}. Tail: last
//  iter waits vmcnt(0).
// ---------------------------------------------------------------------------
#define ES_STRIDE 136
__global__ __launch_bounds__(256, 3)
void proj(const short* __restrict__ Xq, const short* __restrict__ Xk,
          const short* __restrict__ Xv, const short* __restrict__ Wb,
          short* __restrict__ qb, short* __restrict__ kbuf,
          short* __restrict__ vt) {
    __shared__ __align__(16) char lds_raw[49152];
    short8* Fs = (short8*)lds_raw;             // [3][512] bf16 X tiles, 24KB
    short8* Hs = (short8*)(lds_raw + 24576);   // [3][512] bf16 W tiles, 24KB
    short*  Es = (short*)lds_raw;              // epilogue 128 x 136, 34KB

    const int L = blockIdx.x;
    const int xcd = L & 7, i = L >> 3;   // i 0..95
    const int z = i >> 5;                // 0..2
    const int m = i & 31;
    const int ty = xcd * 4 + (m & 3);    // 0..31  (X strip)
    const int tx = m >> 2;               // 0..7   (W strip)

    const short* Fop; const short* Hop; short* C;
    if (z == 0)      { Fop = Xq; Hop = Wb;           C = qb;   }
    else if (z == 1) { Fop = Xk; Hop = Wb + WE;      C = kbuf; }
    else             { Fop = Xv; Hop = Wb + 2 * WE;  C = vt;   }
    const int fr0 = ty * 128;   // X rows
    const int hr0 = tx * 128;   // W rows

    const int t = threadIdx.x, w = t >> 6, lane = t & 63;
    const int l15 = lane & 15, quad = lane >> 4;
    const int mh = (w >> 1) * 64, nh2 = (w & 1) * 64;

    // stage a 128x32 bf16 tile: slot g = c*128 + row (c = 8-elem K chunk),
    // 2 gload16 per thread per operand = 4 wave-level vmem ops per buffer.
    auto stageF = [&](int pp, int k0) {
#pragma unroll
        for (int j = 0; j < 2; ++j) {
            int g = j * 256 + t, row = g & 127, c = g >> 7;
            gload16(Fop + (size_t)(fr0 + row) * EMB + k0 + c * 8,
                    &Fs[pp * 512 + j * 256 + w * 64]);
        }
    };
    auto stageH = [&](int pp, int k0) {
#pragma unroll
        for (int j = 0; j < 2; ++j) {
            int g = j * 256 + t, row = g & 127, c = g >> 7;
            gload16(Hop + (size_t)(hr0 + row) * EMB + k0 + c * 8,
                    &Hs[pp * 512 + j * 256 + w * 64]);
        }
    };

    f32x4 acc[4][4];
#pragma unroll
    for (int a = 0; a < 4; ++a)
#pragma unroll
        for (int b = 0; b < 4; ++b) acc[a][b] = 0.f;

    // prologue: two buffers in flight
    stageF(0, 0);
    stageH(0, 0);
    stageF(1, 32);
    stageH(1, 32);

    int p = 0;
    for (int k0 = 0; k0 < EMB; k0 += 32) {
        // drain exactly this buffer's loads; keep next buffer's in flight
        if (k0 + 32 < EMB) {
            asm volatile("s_waitcnt vmcnt(4)" ::: "memory");
        } else {
            asm volatile("s_waitcnt vmcnt(0)" ::: "memory");
        }
        __builtin_amdgcn_s_barrier();
        __builtin_amdgcn_sched_barrier(0);

        if (k0 + 64 < EMB) {
            int pn = p + 2; if (pn >= 3) pn -= 3;
            stageF(pn, k0 + 64);
            stageH(pn, k0 + 64);
        }

        short8 af[4], bf[4];
        if (z < 2) {
#pragma unroll
            for (int mi = 0; mi < 4; ++mi)
                af[mi] = Fs[p * 512 + quad * 128 + mh + mi * 16 + l15];
#pragma unroll
            for (int ni = 0; ni < 4; ++ni)
                bf[ni] = Hs[p * 512 + quad * 128 + nh2 + ni * 16 + l15];
        } else {
#pragma unroll
            for (int mi = 0; mi < 4; ++mi)
                af[mi] = Hs[p * 512 + quad * 128 + mh + mi * 16 + l15];
#pragma unroll
            for (int ni = 0; ni < 4; ++ni)
                bf[ni] = Fs[p * 512 + quad * 128 + nh2 + ni * 16 + l15];
        }
#pragma unroll
        for (int mi = 0; mi < 4; ++mi)
#pragma unroll
            for (int ni = 0; ni < 4; ++ni)
                acc[mi][ni] = __builtin_amdgcn_mfma_f32_16x16x32_bf16(
                    af[mi], bf[ni], acc[mi][ni], 0, 0, 0);

        p = (p + 1 == 3) ? 0 : p + 1;
    }

    __syncthreads();   // full drain before Es aliases the staging buffers
#pragma unroll
    for (int mi = 0; mi < 4; ++mi)
#pragma unroll
        for (int ni = 0; ni < 4; ++ni)
#pragma unroll
            for (int r = 0; r < 4; ++r) {
                int lr_ = mh + mi * 16 + quad * 4 + r;
                int lc_ = nh2 + ni * 16 + l15;
                Es[lr_ * ES_STRIDE + lc_] = f2bf(acc[mi][ni][r]);
            }
    __syncthreads();
    {
        int row = t >> 1, half = t & 1;
        const short* src = Es + row * ES_STRIDE + half * 64;
        short* dst;
        if (z < 2) {
            dst = C + (size_t)(fr0 + row) * EMB + hr0 + half * 64;
        } else {
            int bz = fr0 >> 11, s0 = fr0 & 2047;
            dst = C + ((size_t)bz * EMB + hr0 + row) * SEQ + s0 + half * 64;
        }
#pragma unroll
        for (int j = 0; j < 8; ++j)
            *(short8*)(dst + j * 8) = *(const short8*)(src + j * 8);
    }
}

// ---------------------------------------------------------------------------
// Flash attention, bf16 MFMA, fixed-max softmax, S^T trick (unchanged).
// ---------------------------------------------------------------------------
__global__ __launch_bounds__(256, 2)
void attn_mfma(const short* __restrict__ Qg, const short* __restrict__ Kg,
               const short* __restrict__ Vtg, float* __restrict__ OutD) {
    __shared__ short8 QPs[1024];     // Q then P: [row(128)][c(8)^] 16KB
    __shared__ short8 Ks[2][1024];   // dbuf [krow(128)][dchunk(8)^] 32KB
    __shared__ short8 Vs[2][1024];   // dbuf [half(2)][drow(64)][kc(8)^] 32KB

    const int t = threadIdx.x, w = t >> 6, lane = t & 63;
    const int l15 = lane & 15, quad = lane >> 4;
    const int lr3 = lane >> 3, lc7 = lane & 7;   // staging row/chunk split
    const int L = blockIdx.x;
    const int xcd = L & 7, i = L >> 3;        // i 0..63
    const int bh = xcd * 4 + (i & 3);         // 0..31
    const int q0 = (i >> 2) * 128;            // 16 q-tiles
    const int b = bh >> 4, h = bh & 15;
    const short* Qb = Qg + (size_t)b * SEQ * EMB + h * HD;
    const short* Kb = Kg + (size_t)b * SEQ * EMB + h * HD;
    const short* Vb = Vtg + ((size_t)b * EMB + h * HD) * SEQ;

    // staging: one gload16 = 8 rows x 128B coalesced, XOR placement
    auto stageKV = [&](int p, int kt) {
#pragma unroll
        for (int j = 0; j < 4; ++j) {
            int rb = w * 32 + j * 8;                 // K key-rows
            int krow = rb + lr3;
            gload16(Kb + (size_t)(kt + krow) * EMB + ((lc7 ^ (krow & 7)) * 8),
                    &Ks[p][rb * 8]);
            int half = w >> 1, db = (w & 1) * 32 + j * 8;   // V d-rows
            int d = db + lr3;
            gload16(Vb + (size_t)d * SEQ + kt + half * 64 + ((lc7 ^ (d & 7)) * 8),
                    &Vs[p][half * 512 + db * 8]);
        }
    };

    // prologue: Q tile + period 0
#pragma unroll
    for (int j = 0; j < 4; ++j) {
        int rb = w * 32 + j * 8;
        int row = rb + lr3;
        gload16(Qb + (size_t)(q0 + row) * EMB + ((lc7 ^ (row & 7)) * 8),
                &QPs[rb * 8]);
    }
    stageKV(0, 0);
    __syncthreads();   // drains prologue loads

    // hoist Q fragments (B-operand, lane l15 = q); wave-private rows, so no
    // barrier needed before P reuses this region.
    short8 qf[2][2];
#pragma unroll
    for (int qi = 0; qi < 2; ++qi)
#pragma unroll
        for (int kb2 = 0; kb2 < 2; ++kb2) {
            int row = w * 32 + qi * 16 + l15;
            qf[qi][kb2] = QPs[row * 8 + ((kb2 * 4 + quad) ^ (l15 & 7))];
        }

    f32x4 o[2][4];
    float lr[2] = {0.f, 0.f};
#pragma unroll
    for (int qi = 0; qi < 2; ++qi)
#pragma unroll
        for (int ni = 0; ni < 4; ++ni) o[qi][ni] = 0.f;
    const float cl2 = 0.18033688011112042f;   // (1/8) * log2(e)
    const float c0  = 11.541560327111707f;    // 64 * cl2

    int p = 0;
    for (int kt = 0; kt < SEQ; kt += 128, p ^= 1) {
        if (kt) __syncthreads();   // drains buf-p loads (issued last period)
        if (kt + 128 < SEQ) stageKV(p ^ 1, kt + 128);

#pragma unroll
        for (int half = 0; half < 2; ++half) {
            // ---- T = K Q^T : rows = key (64 of this half), cols = q ----
            f32x4 s[4][2];
#pragma unroll
            for (int kblk = 0; kblk < 4; ++kblk)
#pragma unroll
                for (int qi = 0; qi < 2; ++qi) s[kblk][qi] = 0.f;
#pragma unroll
            for (int kb2 = 0; kb2 < 2; ++kb2) {
                short8 ak[4];
#pragma unroll
                for (int kblk = 0; kblk < 4; ++kblk) {
                    int row = half * 64 + kblk * 16 + l15;
                    ak[kblk] = Ks[p][row * 8 + ((kb2 * 4 + quad) ^ (l15 & 7))];
                }
#pragma unroll
                for (int kblk = 0; kblk < 4; ++kblk)
#pragma unroll
                    for (int qi = 0; qi < 2; ++qi)
                        s[kblk][qi] = __builtin_amdgcn_mfma_f32_16x16x32_bf16(
                            ak[kblk], qf[qi][kb2], s[kblk][qi], 0, 0, 0);
            }

            // ---- fixed-max softmax + packed b64 P write ----
#pragma unroll
            for (int qi = 0; qi < 2; ++qi) {
                int row = w * 32 + qi * 16 + l15;
#pragma unroll
                for (int kblk = 0; kblk < 4; ++kblk) {
                    float p0 = __builtin_amdgcn_exp2f(fmaf(s[kblk][qi][0], cl2, -c0));
                    float p1 = __builtin_amdgcn_exp2f(fmaf(s[kblk][qi][1], cl2, -c0));
                    float p2 = __builtin_amdgcn_exp2f(fmaf(s[kblk][qi][2], cl2, -c0));
                    float p3 = __builtin_amdgcn_exp2f(fmaf(s[kblk][qi][3], cl2, -c0));
                    lr[qi] += (p0 + p1) + (p2 + p3);
                    uint2 pv; pv.x = pk2(p0, p1); pv.y = pk2(p2, p3);
                    int kc = kblk * 2 + (quad >> 1);
                    *(uint2*)((char*)QPs +
                        (((row * 8 + (kc ^ (l15 & 7))) << 4) | ((quad & 1) << 3)))
                        = pv;
                }
            }
            // no barrier: wave reads back only its own q rows (same-wave RAW)

            // ---- O += P V ----
#pragma unroll
            for (int kb2 = 0; kb2 < 2; ++kb2) {
                short8 ap[2], bv[4];
#pragma unroll
                for (int qi = 0; qi < 2; ++qi) {
                    int row = w * 32 + qi * 16 + l15;
                    ap[qi] = QPs[row * 8 + ((kb2 * 4 + quad) ^ (l15 & 7))];
                }
#pragma unroll
                for (int ni = 0; ni < 4; ++ni) {
                    int dr = ni * 16 + l15;
                    bv[ni] = Vs[p][half * 512 + dr * 8 +
                                   ((kb2 * 4 + quad) ^ (l15 & 7))];
                }
#pragma unroll
                for (int qi = 0; qi < 2; ++qi)
#pragma unroll
                    for (int ni = 0; ni < 4; ++ni)
                        o[qi][ni] = __builtin_amdgcn_mfma_f32_16x16x32_bf16(
                            ap[qi], bv[ni], o[qi][ni], 0, 0, 0);
            }
        }
    }

    // ---- epilogue: reduce l across quads, normalize, store fp32 ----
#pragma unroll
    for (int qi = 0; qi < 2; ++qi) {
        float l = lr[qi];
        l += __shfl_xor(l, 16);
        l += __shfl_xor(l, 32);
        lr[qi] = l;
    }
#pragma unroll
    for (int qi = 0; qi < 2; ++qi)
#pragma unroll
        for (int r = 0; r < 4; ++r) {
            float inv = 1.0f / __shfl(lr[qi], quad * 4 + r);
            int q = q0 + w * 32 + qi * 16 + quad * 4 + r;
            float* op = OutD + ((size_t)b * SEQ + q) * EMB + h * HD;
#pragma unroll
            for (int ni = 0; ni < 4; ++ni)
                op[ni * 16 + l15] = o[qi][ni][r] * inv;
        }
}

// ---------------------------------------------------------------------------
extern "C" void kernel_launch(void* const* d_in, const int* in_sizes, int n_in,
                              void* d_out, int out_size, void* d_ws, size_t ws_size,
                              hipStream_t stream) {
    const float* values  = (const float*)d_in[0];
    const float* keys    = (const float*)d_in[1];
    const float* queries = (const float*)d_in[2];
    const float* Wv      = (const float*)d_in[3];
    const float* Wk      = (const float*)d_in[4];
    const float* Wq      = (const float*)d_in[5];
    float* out = (float*)d_out;

    // ws: qb, kb, vt (8MB each) + wb (6MB) + xq, xk, xv bf16 (8MB each) = 54MB
    short* qb  = (short*)d_ws;
    short* kb  = qb + XE;
    short* vt  = kb + XE;
    short* wb  = vt + XE;          // 3*WE
    short* xqb = wb + 3 * WE;
    short* xkb = xqb + XE;
    short* xvb = xkb + XE;

    cvt_all<<<7680, 256, 0, stream>>>(queries, keys, values, Wq, Wk, Wv,
                                      xqb, xkb, xvb, wb);
    proj<<<768, 256, 0, stream>>>(xqb, xkb, xvb, wb, qb, kb, vt);
    attn_mfma<<<512, 256, 0, stream>>>(qb, kb, vt, out);
}

// Round 5
// 188.870 us; speedup vs baseline: 1.1546x; 1.1134x over previous
//
#include <hip/hip_runtime.h>
#include <math.h>

#define SEQ 2048
#define EMB 1024
#define NH  16
#define HD  64

typedef __attribute__((ext_vector_type(8))) short short8;   // 8 bf16 = 4 VGPRs
typedef __attribute__((ext_vector_type(4))) float f32x4;    // MFMA acc

static const size_t XE = (size_t)2 * SEQ * EMB;  // 4,194,304 elems
static const size_t WE = (size_t)EMB * EMB;      // 1,048,576 elems

// RNE float -> bf16 bits (inputs finite)
static __device__ __forceinline__ short f2bf(float f) {
    unsigned u = __builtin_bit_cast(unsigned, f);
    u = u + 0x7fffu + ((u >> 16) & 1u);
    return (short)(u >> 16);
}

#if __has_builtin(__builtin_amdgcn_cvt_pk_bf16_f32)
typedef __attribute__((ext_vector_type(2))) __bf16 bf16x2;
static __device__ __forceinline__ unsigned pk2(float a, float b) {
    bf16x2 v = __builtin_amdgcn_cvt_pk_bf16_f32(a, b);
    return __builtin_bit_cast(unsigned, v);
}
#else
static __device__ __forceinline__ unsigned pk2(float a, float b) {
    return (unsigned)(unsigned short)f2bf(a) |
           ((unsigned)(unsigned short)f2bf(b) << 16);
}
#endif

static __device__ __forceinline__ short8 cvt8(float4 a, float4 b) {
    union { unsigned u[4]; short8 s; } r;
    r.u[0] = pk2(a.x, a.y); r.u[1] = pk2(a.z, a.w);
    r.u[2] = pk2(b.x, b.y); r.u[3] = pk2(b.z, b.w);
    return r.s;
}

// async global->LDS, 16B/lane; LDS dest = wave-uniform base + lane*16
static __device__ __forceinline__ void gload16(const void* g, void* l) {
    __builtin_amdgcn_global_load_lds(
        (const __attribute__((address_space(1))) void*)g,
        (__attribute__((address_space(3))) void*)l, 16, 0, 0);
}

// ---------------------------------------------------------------------------
// Pre-pass: convert X (q,k,v activations) AND the three weight matrices to
// bf16. Memory-bound (~90MB total), layout-preserving.
//   blocks [0,6144): X   (3 segs x 2048 blocks, 4M elems each)
//   blocks [6144,7680): W (3 segs x 512 blocks, 1M elems each)
// ---------------------------------------------------------------------------
__global__ __launch_bounds__(256)
void cvt_all(const float* __restrict__ xq, const float* __restrict__ xk,
             const float* __restrict__ xv, const float* __restrict__ wq,
             const float* __restrict__ wk, const float* __restrict__ wv,
             short* __restrict__ dxq, short* __restrict__ dxk,
             short* __restrict__ dxv, short* __restrict__ dw) {
    int id = blockIdx.x;
    const float* s; short* d; size_t i;
    if (id < 6144) {
        int seg = id >> 11, o = id & 2047;
        s = (seg == 0) ? xq : (seg == 1) ? xk : xv;
        d = (seg == 0) ? dxq : (seg == 1) ? dxk : dxv;
        i = (size_t)o * 256 + threadIdx.x;
    } else {
        int wid = id - 6144;
        int seg = wid >> 9, o = wid & 511;
        s = (seg == 0) ? wq : (seg == 1) ? wk : wv;
        d = dw + (size_t)seg * WE;
        i = (size_t)o * 256 + threadIdx.x;
    }
    const float4* sp = (const float4*)s;
    float4 a = sp[2 * i], b = sp[2 * i + 1];
    *(short8*)(d + i * 8) = cvt8(a, b);
}

// ---------------------------------------------------------------------------
// Projection GEMM, round 11: COALESCED staging (the r8-r10 chunk-major
// staging was 64 lanes x stride-2KB per global_load_lds = 8x L2 sector
// over-fetch ~ 50 TB/s demand > 34.5 TB/s L2 ceiling — the invariant that
// capped rounds 8-10 at ~62-64us).
//  - BK=64: one row's K-slice = 128B; one gload16 = 8 rows x 128B fully
//    coalesced (attn's verified stageKV pattern).
//  - LDS row-major [row(128)][chunk(8)] per operand, involution XOR on the
//    GLOBAL source (chunk = lc7 ^ lr3); fragment read at
//    slot = row*8 + (c ^ (row&7)) -> 2-way banked (free).
//  - 8 waves (512 thr), wave tile 64x32, acc 4x2 -> 16 waves/CU TLP.
//  - plain verified dbuf skeleton: barrier -> prefetch p^1 -> ds_read p ->
//    MFMA. No exotic waits.
// ---------------------------------------------------------------------------
#define ES_STRIDE 136
__global__ __launch_bounds__(512, 4)
void proj(const short* __restrict__ Xq, const short* __restrict__ Xk,
          const short* __restrict__ Xv, const short* __restrict__ Wb,
          short* __restrict__ qb, short* __restrict__ kbuf,
          short* __restrict__ vt) {
    __shared__ __align__(16) char lds_raw[65536];
    short8* Fs = (short8*)lds_raw;             // [2][128][8] bf16 X, 32KB
    short8* Hs = (short8*)(lds_raw + 32768);   // [2][128][8] bf16 W, 32KB
    short*  Es = (short*)lds_raw;              // epilogue 128 x 136, 34KB

    const int L = blockIdx.x;
    const int xcd = L & 7, i = L >> 3;   // i 0..95
    const int z = i >> 5;                // 0..2
    const int m = i & 31;
    const int ty = xcd * 4 + (m & 3);    // 0..31  (X strip)
    const int tx = m >> 2;               // 0..7   (W strip)

    const short* Fop; const short* Hop; short* C;
    if (z == 0)      { Fop = Xq; Hop = Wb;           C = qb;   }
    else if (z == 1) { Fop = Xk; Hop = Wb + WE;      C = kbuf; }
    else             { Fop = Xv; Hop = Wb + 2 * WE;  C = vt;   }
    const int fr0 = ty * 128;   // X rows
    const int hr0 = tx * 128;   // W rows

    const int t = threadIdx.x, w = t >> 6, lane = t & 63;
    const int l15 = lane & 15, quad = lane >> 4;
    const int lr3 = lane >> 3, lc7 = lane & 7;   // staging: 8 rows x 8 chunks
    const int mh = (w >> 2) * 64;        // wave row base (2 row-groups)
    const int nh = (w & 3) * 32;         // wave col base (4 col-groups)

    // stage a 128x64 bf16 tile, fully coalesced: one gload16 = 8 rows x
    // 128B contiguous. LDS row-major [row][chunk]; source pre-swizzled so
    // slot row*8+lc7 holds chunk (lc7 ^ (row&7)).
    auto stageF = [&](int pp, int k0) {
#pragma unroll
        for (int j = 0; j < 2; ++j) {
            int rb = j * 64 + w * 8;
            gload16(Fop + (size_t)(fr0 + rb + lr3) * EMB + k0 + ((lc7 ^ lr3) * 8),
                    &Fs[pp * 1024 + rb * 8]);
        }
    };
    auto stageH = [&](int pp, int k0) {
#pragma unroll
        for (int j = 0; j < 2; ++j) {
            int rb = j * 64 + w * 8;
            gload16(Hop + (size_t)(hr0 + rb + lr3) * EMB + k0 + ((lc7 ^ lr3) * 8),
                    &Hs[pp * 1024 + rb * 8]);
        }
    };

    f32x4 acc[4][2];
#pragma unroll
    for (int a = 0; a < 4; ++a)
#pragma unroll
        for (int b = 0; b < 2; ++b) acc[a][b] = 0.f;

    stageF(0, 0);
    stageH(0, 0);

    int p = 0;
    for (int k0 = 0; k0 < EMB; k0 += 64, p ^= 1) {
        __syncthreads();   // drains prev-iter gload_lds into buffer p
        if (k0 + 64 < EMB) { stageF(p ^ 1, k0 + 64); stageH(p ^ 1, k0 + 64); }

#pragma unroll
        for (int kb2 = 0; kb2 < 2; ++kb2) {
            short8 af[4], bf[2];
            int cx = (kb2 * 4 + quad) ^ (l15 & 7);   // row&7 == l15&7
            if (z < 2) {
#pragma unroll
                for (int mi = 0; mi < 4; ++mi)
                    af[mi] = Fs[p * 1024 + (mh + mi * 16 + l15) * 8 + cx];
#pragma unroll
                for (int ni = 0; ni < 2; ++ni)
                    bf[ni] = Hs[p * 1024 + (nh + ni * 16 + l15) * 8 + cx];
            } else {
#pragma unroll
                for (int mi = 0; mi < 4; ++mi)
                    af[mi] = Hs[p * 1024 + (mh + mi * 16 + l15) * 8 + cx];
#pragma unroll
                for (int ni = 0; ni < 2; ++ni)
                    bf[ni] = Fs[p * 1024 + (nh + ni * 16 + l15) * 8 + cx];
            }
#pragma unroll
            for (int mi = 0; mi < 4; ++mi)
#pragma unroll
                for (int ni = 0; ni < 2; ++ni)
                    acc[mi][ni] = __builtin_amdgcn_mfma_f32_16x16x32_bf16(
                        af[mi], bf[ni], acc[mi][ni], 0, 0, 0);
        }
    }

    __syncthreads();   // all reads done before Es aliases staging buffers
#pragma unroll
    for (int mi = 0; mi < 4; ++mi)
#pragma unroll
        for (int ni = 0; ni < 2; ++ni)
#pragma unroll
            for (int r = 0; r < 4; ++r) {
                int lr_ = mh + mi * 16 + quad * 4 + r;
                int lc_ = nh + ni * 16 + l15;
                Es[lr_ * ES_STRIDE + lc_] = f2bf(acc[mi][ni][r]);
            }
    __syncthreads();
    {
        int row = t >> 2, q4 = t & 3;        // 128 rows x 4 quarters of 32
        const short* src = Es + row * ES_STRIDE + q4 * 32;
        short* dst;
        if (z < 2) {
            dst = C + (size_t)(fr0 + row) * EMB + hr0 + q4 * 32;
        } else {
            int bz = fr0 >> 11, s0 = fr0 & 2047;
            dst = C + ((size_t)bz * EMB + hr0 + row) * SEQ + s0 + q4 * 32;
        }
#pragma unroll
        for (int j = 0; j < 4; ++j)
            *(short8*)(dst + j * 8) = *(const short8*)(src + j * 8);
    }
}

// ---------------------------------------------------------------------------
// Flash attention, bf16 MFMA, fixed-max softmax, S^T trick (unchanged).
// ---------------------------------------------------------------------------
__global__ __launch_bounds__(256, 2)
void attn_mfma(const short* __restrict__ Qg, const short* __restrict__ Kg,
               const short* __restrict__ Vtg, float* __restrict__ OutD) {
    __shared__ short8 QPs[1024];     // Q then P: [row(128)][c(8)^] 16KB
    __shared__ short8 Ks[2][1024];   // dbuf [krow(128)][dchunk(8)^] 32KB
    __shared__ short8 Vs[2][1024];   // dbuf [half(2)][drow(64)][kc(8)^] 32KB

    const int t = threadIdx.x, w = t >> 6, lane = t & 63;
    const int l15 = lane & 15, quad = lane >> 4;
    const int lr3 = lane >> 3, lc7 = lane & 7;   // staging row/chunk split
    const int L = blockIdx.x;
    const int xcd = L & 7, i = L >> 3;        // i 0..63
    const int bh = xcd * 4 + (i & 3);         // 0..31
    const int q0 = (i >> 2) * 128;            // 16 q-tiles
    const int b = bh >> 4, h = bh & 15;
    const short* Qb = Qg + (size_t)b * SEQ * EMB + h * HD;
    const short* Kb = Kg + (size_t)b * SEQ * EMB + h * HD;
    const short* Vb = Vtg + ((size_t)b * EMB + h * HD) * SEQ;

    // staging: one gload16 = 8 rows x 128B coalesced, XOR placement
    auto stageKV = [&](int p, int kt) {
#pragma unroll
        for (int j = 0; j < 4; ++j) {
            int rb = w * 32 + j * 8;                 // K key-rows
            int krow = rb + lr3;
            gload16(Kb + (size_t)(kt + krow) * EMB + ((lc7 ^ (krow & 7)) * 8),
                    &Ks[p][rb * 8]);
            int half = w >> 1, db = (w & 1) * 32 + j * 8;   // V d-rows
            int d = db + lr3;
            gload16(Vb + (size_t)d * SEQ + kt + half * 64 + ((lc7 ^ (d & 7)) * 8),
                    &Vs[p][half * 512 + db * 8]);
        }
    };

    // prologue: Q tile + period 0
#pragma unroll
    for (int j = 0; j < 4; ++j) {
        int rb = w * 32 + j * 8;
        int row = rb + lr3;
        gload16(Qb + (size_t)(q0 + row) * EMB + ((lc7 ^ (row & 7)) * 8),
                &QPs[rb * 8]);
    }
    stageKV(0, 0);
    __syncthreads();   // drains prologue loads

    // hoist Q fragments (B-operand, lane l15 = q); wave-private rows, so no
    // barrier needed before P reuses this region.
    short8 qf[2][2];
#pragma unroll
    for (int qi = 0; qi < 2; ++qi)
#pragma unroll
        for (int kb2 = 0; kb2 < 2; ++kb2) {
            int row = w * 32 + qi * 16 + l15;
            qf[qi][kb2] = QPs[row * 8 + ((kb2 * 4 + quad) ^ (l15 & 7))];
        }

    f32x4 o[2][4];
    float lr[2] = {0.f, 0.f};
#pragma unroll
    for (int qi = 0; qi < 2; ++qi)
#pragma unroll
        for (int ni = 0; ni < 4; ++ni) o[qi][ni] = 0.f;
    const float cl2 = 0.18033688011112042f;   // (1/8) * log2(e)
    const float c0  = 11.541560327111707f;    // 64 * cl2

    int p = 0;
    for (int kt = 0; kt < SEQ; kt += 128, p ^= 1) {
        if (kt) __syncthreads();   // drains buf-p loads (issued last period)
        if (kt + 128 < SEQ) stageKV(p ^ 1, kt + 128);

#pragma unroll
        for (int half = 0; half < 2; ++half) {
            // ---- T = K Q^T : rows = key (64 of this half), cols = q ----
            f32x4 s[4][2];
#pragma unroll
            for (int kblk = 0; kblk < 4; ++kblk)
#pragma unroll
                for (int qi = 0; qi < 2; ++qi) s[kblk][qi] = 0.f;
#pragma unroll
            for (int kb2 = 0; kb2 < 2; ++kb2) {
                short8 ak[4];
#pragma unroll
                for (int kblk = 0; kblk < 4; ++kblk) {
                    int row = half * 64 + kblk * 16 + l15;
                    ak[kblk] = Ks[p][row * 8 + ((kb2 * 4 + quad) ^ (l15 & 7))];
                }
#pragma unroll
                for (int kblk = 0; kblk < 4; ++kblk)
#pragma unroll
                    for (int qi = 0; qi < 2; ++qi)
                        s[kblk][qi] = __builtin_amdgcn_mfma_f32_16x16x32_bf16(
                            ak[kblk], qf[qi][kb2], s[kblk][qi], 0, 0, 0);
            }

            // ---- fixed-max softmax + packed b64 P write ----
#pragma unroll
            for (int qi = 0; qi < 2; ++qi) {
                int row = w * 32 + qi * 16 + l15;
#pragma unroll
                for (int kblk = 0; kblk < 4; ++kblk) {
                    float p0 = __builtin_amdgcn_exp2f(fmaf(s[kblk][qi][0], cl2, -c0));
                    float p1 = __builtin_amdgcn_exp2f(fmaf(s[kblk][qi][1], cl2, -c0));
                    float p2 = __builtin_amdgcn_exp2f(fmaf(s[kblk][qi][2], cl2, -c0));
                    float p3 = __builtin_amdgcn_exp2f(fmaf(s[kblk][qi][3], cl2, -c0));
                    lr[qi] += (p0 + p1) + (p2 + p3);
                    uint2 pv; pv.x = pk2(p0, p1); pv.y = pk2(p2, p3);
                    int kc = kblk * 2 + (quad >> 1);
                    *(uint2*)((char*)QPs +
                        (((row * 8 + (kc ^ (l15 & 7))) << 4) | ((quad & 1) << 3)))
                        = pv;
                }
            }
            // no barrier: wave reads back only its own q rows (same-wave RAW)

            // ---- O += P V ----
#pragma unroll
            for (int kb2 = 0; kb2 < 2; ++kb2) {
                short8 ap[2], bv[4];
#pragma unroll
                for (int qi = 0; qi < 2; ++qi) {
                    int row = w * 32 + qi * 16 + l15;
                    ap[qi] = QPs[row * 8 + ((kb2 * 4 + quad) ^ (l15 & 7))];
                }
#pragma unroll
                for (int ni = 0; ni < 4; ++ni) {
                    int dr = ni * 16 + l15;
                    bv[ni] = Vs[p][half * 512 + dr * 8 +
                                   ((kb2 * 4 + quad) ^ (l15 & 7))];
                }
#pragma unroll
                for (int qi = 0; qi < 2; ++qi)
#pragma unroll
                    for (int ni = 0; ni < 4; ++ni)
                        o[qi][ni] = __builtin_amdgcn_mfma_f32_16x16x32_bf16(
                            ap[qi], bv[ni], o[qi][ni], 0, 0, 0);
            }
        }
    }

    // ---- epilogue: reduce l across quads, normalize, store fp32 ----
#pragma unroll
    for (int qi = 0; qi < 2; ++qi) {
        float l = lr[qi];
        l += __shfl_xor(l, 16);
        l += __shfl_xor(l, 32);
        lr[qi] = l;
    }
#pragma unroll
    for (int qi = 0; qi < 2; ++qi)
#pragma unroll
        for (int r = 0; r < 4; ++r) {
            float inv = 1.0f / __shfl(lr[qi], quad * 4 + r);
            int q = q0 + w * 32 + qi * 16 + quad * 4 + r;
            float* op = OutD + ((size_t)b * SEQ + q) * EMB + h * HD;
#pragma unroll
            for (int ni = 0; ni < 4; ++ni)
                op[ni * 16 + l15] = o[qi][ni][r] * inv;
        }
}

// ---------------------------------------------------------------------------
extern "C" void kernel_launch(void* const* d_in, const int* in_sizes, int n_in,
                              void* d_out, int out_size, void* d_ws, size_t ws_size,
                              hipStream_t stream) {
    const float* values  = (const float*)d_in[0];
    const float* keys    = (const float*)d_in[1];
    const float* queries = (const float*)d_in[2];
    const float* Wv      = (const float*)d_in[3];
    const float* Wk      = (const float*)d_in[4];
    const float* Wq      = (const float*)d_in[5];
    float* out = (float*)d_out;

    // ws: qb, kb, vt (8MB each) + wb (6MB) + xq, xk, xv bf16 (8MB each) = 54MB
    short* qb  = (short*)d_ws;
    short* kb  = qb + XE;
    short* vt  = kb + XE;
    short* wb  = vt + XE;          // 3*WE
    short* xqb = wb + 3 * WE;
    short* xkb = xqb + XE;
    short* xvb = xkb + XE;

    cvt_all<<<7680, 256, 0, stream>>>(queries, keys, values, Wq, Wk, Wv,
                                      xqb, xkb, xvb, wb);
    proj<<<768, 512, 0, stream>>>(xqb, xkb, xvb, wb, qb, kb, vt);
    attn_mfma<<<512, 256, 0, stream>>>(qb, kb, vt, out);
}